// Round 1
// baseline (578.666 us; speedup 1.0000x reference)
//
#include <hip/hip_runtime.h>

#define NN 50000
#define NE 800000
#define C 128
#define NTT 8
#define ETT 16
#define HH 64
#define TIN 288
#define LN_EPS 1e-5f

// ---------------- prep: fold ln_w into W1, precompute s_j and c_j -------------
__global__ void prep_kernel(const float* __restrict__ ln_w,
                            const float* __restrict__ ln_b,
                            const float* __restrict__ W1,
                            const float* __restrict__ b1,
                            float* __restrict__ W1p,   // [288][64]
                            float* __restrict__ sj,    // [64]
                            float* __restrict__ cj) {  // [64]
    int j = threadIdx.x;  // 64 threads
    float s = 0.f, c = 0.f;
    for (int k = 0; k < TIN; ++k) {
        float w  = W1[k * HH + j];
        float wp = ln_w[k] * w;
        W1p[k * HH + j] = wp;
        s += wp;
        c += ln_b[k] * w;
    }
    sj[j] = s;
    cj[j] = c + b1[j];
}

// ---------------- main: one thread per edge ----------------------------------
__global__ void edge_kernel(const float* __restrict__ x,      // [N][128]
                            const int*   __restrict__ ei,     // [2][E]
                            const int*   __restrict__ etype,  // [E]
                            const int*   __restrict__ ntype,  // [N]
                            const float* __restrict__ W1p,    // [288][64]
                            const float* __restrict__ sj,     // [64]
                            const float* __restrict__ cj,     // [64]
                            const float* __restrict__ W2,     // [64][16]
                            const float* __restrict__ b2,     // [16]
                            float* __restrict__ out) {        // [E][16]
    int e = blockIdx.x * blockDim.x + threadIdx.x;
    if (e >= NE) return;

    int row = ei[e];
    int col = ei[NE + e];

    float hid[HH];
#pragma unroll
    for (int j = 0; j < HH; ++j) hid[j] = 0.f;

    // one-hot features contribute exactly three 1.0 entries
    float sum = 3.0f, sumsq = 3.0f;

    const float4* xr = reinterpret_cast<const float4*>(x + (size_t)row * C);
    const float4* xc = reinterpret_cast<const float4*>(x + (size_t)col * C);

    for (int k4 = 0; k4 < C / 4; ++k4) {  // 32 iterations, 8 features each
        float4 a = xr[k4];
        float4 b = xc[k4];
        sum   += (a.x + a.y) + (a.z + a.w) + (b.x + b.y) + (b.z + b.w);
        sumsq += (a.x * a.x + a.y * a.y) + (a.z * a.z + a.w * a.w)
               + (b.x * b.x + b.y * b.y) + (b.z * b.z + b.w * b.w);
        float av[4] = {a.x, a.y, a.z, a.w};
        float bv[4] = {b.x, b.y, b.z, b.w};
        const float* wa = W1p + (k4 * 4) * HH;        // rows k4*4 .. +3
        const float* wb = W1p + (C + k4 * 4) * HH;    // rows 128+k4*4 .. +3
#pragma unroll
        for (int u = 0; u < 4; ++u) {
#pragma unroll
            for (int j = 0; j < HH; ++j) hid[j] += av[u] * wa[u * HH + j];
#pragma unroll
            for (int j = 0; j < HH; ++j) hid[j] += bv[u] * wb[u * HH + j];
        }
    }

    // one-hot rows (divergent per-lane gathers; 32 rows * 256B, L1-resident)
    int ntr = ntype[row];
    int ntc = ntype[col];
    int et  = etype[e];
    const float4* wr4 = reinterpret_cast<const float4*>(W1p + (2 * C + ntr) * HH);
    const float4* wc4 = reinterpret_cast<const float4*>(W1p + (2 * C + NTT + ntc) * HH);
    const float4* we4 = reinterpret_cast<const float4*>(W1p + (2 * C + 2 * NTT + et) * HH);
#pragma unroll
    for (int j4 = 0; j4 < HH / 4; ++j4) {
        float4 pr = wr4[j4];
        float4 pc = wc4[j4];
        float4 pe = we4[j4];
        hid[j4 * 4 + 0] += pr.x + pc.x + pe.x;
        hid[j4 * 4 + 1] += pr.y + pc.y + pe.y;
        hid[j4 * 4 + 2] += pr.z + pc.z + pe.z;
        hid[j4 * 4 + 3] += pr.w + pc.w + pe.w;
    }

    float mu   = sum * (1.0f / TIN);
    float var  = sumsq * (1.0f / TIN) - mu * mu;
    float rstd = rsqrtf(var + LN_EPS);

    // second layer: 64 -> 16, with relu on hidden
    float o[16];
#pragma unroll
    for (int d = 0; d < 16; ++d) o[d] = b2[d];
#pragma unroll
    for (int j = 0; j < HH; ++j) {
        float hj = rstd * (hid[j] - mu * sj[j]) + cj[j];
        hj = fmaxf(hj, 0.0f);
        const float* w2r = W2 + j * 16;
#pragma unroll
        for (int d = 0; d < 16; ++d) o[d] += hj * w2r[d];
    }

    // per-row softmax over 4, out = I - softmax
    float res[16];
#pragma unroll
    for (int r = 0; r < 4; ++r) {
        float v0 = o[r * 4 + 0], v1 = o[r * 4 + 1], v2 = o[r * 4 + 2], v3 = o[r * 4 + 3];
        float m  = fmaxf(fmaxf(v0, v1), fmaxf(v2, v3));
        float e0 = __expf(v0 - m), e1 = __expf(v1 - m), e2 = __expf(v2 - m), e3 = __expf(v3 - m);
        float inv = 1.0f / (e0 + e1 + e2 + e3);
        res[r * 4 + 0] = (r == 0 ? 1.0f : 0.0f) - e0 * inv;
        res[r * 4 + 1] = (r == 1 ? 1.0f : 0.0f) - e1 * inv;
        res[r * 4 + 2] = (r == 2 ? 1.0f : 0.0f) - e2 * inv;
        res[r * 4 + 3] = (r == 3 ? 1.0f : 0.0f) - e3 * inv;
    }

    float4* op = reinterpret_cast<float4*>(out + (size_t)e * 16);
    op[0] = make_float4(res[0],  res[1],  res[2],  res[3]);
    op[1] = make_float4(res[4],  res[5],  res[6],  res[7]);
    op[2] = make_float4(res[8],  res[9],  res[10], res[11]);
    op[3] = make_float4(res[12], res[13], res[14], res[15]);
}

extern "C" void kernel_launch(void* const* d_in, const int* in_sizes, int n_in,
                              void* d_out, int out_size, void* d_ws, size_t ws_size,
                              hipStream_t stream) {
    const float* x     = (const float*)d_in[0];
    const int*   ei    = (const int*)d_in[1];
    const int*   etype = (const int*)d_in[2];
    const int*   ntype = (const int*)d_in[3];
    const float* ln_w  = (const float*)d_in[4];
    const float* ln_b  = (const float*)d_in[5];
    const float* W1    = (const float*)d_in[6];
    const float* b1    = (const float*)d_in[7];
    const float* W2    = (const float*)d_in[8];
    const float* b2    = (const float*)d_in[9];
    float* out = (float*)d_out;

    float* W1p = (float*)d_ws;             // 288*64 floats
    float* sj  = W1p + TIN * HH;           // 64
    float* cj  = sj + HH;                  // 64

    prep_kernel<<<1, HH, 0, stream>>>(ln_w, ln_b, W1, b1, W1p, sj, cj);

    int block = 256;
    int grid  = (NE + block - 1) / block;
    edge_kernel<<<grid, block, 0, stream>>>(x, ei, etype, ntype, W1p, sj, cj,
                                            W2, b2, out);
}

// Round 2
// 155.773 us; speedup vs baseline: 3.7148x; 3.7148x over previous
//
#include <hip/hip_runtime.h>
#include <hip/hip_bf16.h>

#define NN 50000
#define NE 800000
#define C 128
#define HH 64
#define TIN 288
#define LN_EPS 1e-5f

typedef __attribute__((ext_vector_type(8))) short bf16x8;
typedef __attribute__((ext_vector_type(4))) float f32x4;

// ws layout (bytes):
//   [0,256)       sj[64] f32
//   [256,512)     cj[64] f32
//   [512,37376)   B1frag: [kt=9][nt=4][lane=64][j=8] bf16  (36864 B)
//   [37376,39424) B2frag: [kt=2][lane=64][j=8] bf16        (2048 B)

__device__ __forceinline__ short f2bf(float f) {
    __hip_bfloat16 h = __float2bfloat16(f);
    return __builtin_bit_cast(short, h);
}

__global__ void prep_kernel(const float* __restrict__ ln_w,
                            const float* __restrict__ ln_b,
                            const float* __restrict__ W1,
                            const float* __restrict__ b1,
                            const float* __restrict__ W2,
                            float* __restrict__ ws) {
    int l = threadIdx.x;        // 64 lanes
    int m = l & 15, g = l >> 4;
    float s = 0.f, c = 0.f;
    for (int k = 0; k < TIN; ++k) {
        float w = W1[k * HH + l];
        s += ln_w[k] * w;
        c += ln_b[k] * w;
    }
    ws[l] = s;
    ws[64 + l] = c + b1[l];

    short* B1 = (short*)((char*)ws + 512);
    for (int kt = 0; kt < 9; ++kt)
        for (int nt = 0; nt < 4; ++nt)
            for (int j = 0; j < 8; ++j) {
                int k = 32 * kt + 8 * g + j;
                int n = 16 * nt + m;
                B1[((kt * 4 + nt) * 64 + l) * 8 + j] = f2bf(ln_w[k] * W1[k * HH + n]);
            }
    short* B2 = B1 + 18432;
    for (int kt = 0; kt < 2; ++kt)
        for (int j = 0; j < 8; ++j) {
            int k = 32 * kt + 8 * g + j;
            B2[(kt * 64 + l) * 8 + j] = f2bf(W2[k * 16 + m]);
        }
}

__global__ __launch_bounds__(512, 4) void edge_kernel(
    const float* __restrict__ x,      // [N][128]
    const int* __restrict__ ei,       // [2][E]
    const int* __restrict__ etype,    // [E]
    const int* __restrict__ ntype,    // [N]
    const float* __restrict__ ws,     // sj/cj/B1/B2
    const float* __restrict__ b2,     // [16]
    float* __restrict__ out) {        // [E][16]
    // LDS: B1 (18432 shorts) | B2 (1024 shorts) | hT (8 waves * 1024 shorts)
    __shared__ __align__(16) short lds_s[27648];

    int tid = threadIdx.x;
    {   // stage B1+B2 fragments (38912 B) into LDS
        const float4* src = (const float4*)((const char*)ws + 512);
        float4* dst = (float4*)lds_s;
        for (int i = tid; i < 2432; i += 512) dst[i] = src[i];
    }
    __syncthreads();

    int wave = tid >> 6, lane = tid & 63;
    int m = lane & 15, g = lane >> 4;
    int tile = blockIdx.x * 128 + wave * 16;
    int e = tile + m;

    int row = ei[e];
    int col = ei[NE + e];
    int ntr = ntype[row], ntc = ntype[col], et = etype[e];

    f32x4 acc0 = {0.f, 0.f, 0.f, 0.f};
    f32x4 acc1 = {0.f, 0.f, 0.f, 0.f};
    f32x4 acc2t = {0.f, 0.f, 0.f, 0.f};
    f32x4 acc3 = {0.f, 0.f, 0.f, 0.f};
    float sum = 0.f, sumsq = 0.f;

#pragma unroll
    for (int kt = 0; kt < 9; ++kt) {
        bf16x8 af;
        if (kt < 8) {
            const float* base = x + (size_t)(kt < 4 ? row : col) * C + (kt & 3) * 32 + g * 8;
            float4 p0 = *(const float4*)base;
            float4 p1 = *(const float4*)(base + 4);
            float v[8] = {p0.x, p0.y, p0.z, p0.w, p1.x, p1.y, p1.z, p1.w};
#pragma unroll
            for (int j = 0; j < 8; ++j) {
                sum += v[j];
                sumsq = fmaf(v[j], v[j], sumsq);
                af[j] = f2bf(v[j]);
            }
        } else {
            int sel = (g == 0) ? ntr : (g == 1) ? ntc : (g == 2) ? et : (et - 8);
#pragma unroll
            for (int j = 0; j < 8; ++j) af[j] = (j == sel) ? (short)0x3F80 : (short)0;
        }
        const bf16x8* Bk = (const bf16x8*)(lds_s + kt * 2048);
        acc0 = __builtin_amdgcn_mfma_f32_16x16x32_bf16(af, Bk[0 * 64 + lane], acc0, 0, 0, 0);
        acc1 = __builtin_amdgcn_mfma_f32_16x16x32_bf16(af, Bk[1 * 64 + lane], acc1, 0, 0, 0);
        acc2t = __builtin_amdgcn_mfma_f32_16x16x32_bf16(af, Bk[2 * 64 + lane], acc2t, 0, 0, 0);
        acc3 = __builtin_amdgcn_mfma_f32_16x16x32_bf16(af, Bk[3 * 64 + lane], acc3, 0, 0, 0);
    }

    // LN stats: lane covered k-slices of edge m; reduce across the 4 g-groups
    sum += __shfl_xor(sum, 16);
    sum += __shfl_xor(sum, 32);
    sumsq += __shfl_xor(sumsq, 16);
    sumsq += __shfl_xor(sumsq, 32);
    sum += 3.0f;    // three one-hot 1.0 entries
    sumsq += 3.0f;
    float mu = sum * (1.0f / TIN);
    float var = sumsq * (1.0f / TIN) - mu * mu;
    float rstd = rsqrtf(var + LN_EPS);

    // D rows held by this lane are edges 4g+i; pull their stats
    float muv[4], rsv[4];
#pragma unroll
    for (int i = 0; i < 4; ++i) {
        muv[i] = __shfl(mu, 4 * g + i);
        rsv[i] = __shfl(rstd, 4 * g + i);
    }
    // per-column s_j, c_j (col = 16*nt + m)
    float sjv[4], cjv[4];
#pragma unroll
    for (int nt = 0; nt < 4; ++nt) {
        sjv[nt] = ws[16 * nt + m];
        cjv[nt] = ws[64 + 16 * nt + m];
    }

    // hid = relu(rstd*(G - mu*s) + c) -> bf16 -> swizzled LDS transpose
    short* hTw = lds_s + 19456 + wave * 1024;
    f32x4 accs[4] = {acc0, acc1, acc2t, acc3};
#pragma unroll
    for (int nt = 0; nt < 4; ++nt) {
#pragma unroll
        for (int i = 0; i < 4; ++i) {
            float hv = rsv[i] * (accs[nt][i] - muv[i] * sjv[nt]) + cjv[nt];
            hv = fmaxf(hv, 0.0f);
            int erow = 4 * g + i;
            int sidx = (erow * 64 + 16 * nt + m) ^ ((erow & 7) << 3);
            hTw[sidx] = f2bf(hv);
        }
    }
    __syncthreads();

    // GEMM2: [16 edges x 64] @ W2[64][16]
    f32x4 o = {0.f, 0.f, 0.f, 0.f};
    const bf16x8* B2f = (const bf16x8*)(lds_s + 18432);
#pragma unroll
    for (int kt2 = 0; kt2 < 2; ++kt2) {
        int sbase = (m * 64 + kt2 * 32 + 8 * g) ^ ((m & 7) << 3);
        bf16x8 a2 = *(const bf16x8*)(hTw + sbase);
        o = __builtin_amdgcn_mfma_f32_16x16x32_bf16(a2, B2f[kt2 * 64 + lane], o, 0, 0, 0);
    }

    // epilogue: +b2, per-4 softmax across lanes, out = I - softmax
    float b2v = b2[m];
    int r = m >> 2, cc = m & 3;
    float diag = (cc == r) ? 1.0f : 0.0f;
#pragma unroll
    for (int i = 0; i < 4; ++i) {
        float v = o[i] + b2v;
        float mx = fmaxf(v, __shfl_xor(v, 1));
        mx = fmaxf(mx, __shfl_xor(mx, 2));
        float ev = __expf(v - mx);
        float s = ev + __shfl_xor(ev, 1);
        s += __shfl_xor(s, 2);
        out[(size_t)(tile + 4 * g + i) * 16 + m] = diag - ev / s;
    }
}

extern "C" void kernel_launch(void* const* d_in, const int* in_sizes, int n_in,
                              void* d_out, int out_size, void* d_ws, size_t ws_size,
                              hipStream_t stream) {
    const float* x     = (const float*)d_in[0];
    const int*   ei    = (const int*)d_in[1];
    const int*   etype = (const int*)d_in[2];
    const int*   ntype = (const int*)d_in[3];
    const float* ln_w  = (const float*)d_in[4];
    const float* ln_b  = (const float*)d_in[5];
    const float* W1    = (const float*)d_in[6];
    const float* b1    = (const float*)d_in[7];
    const float* W2    = (const float*)d_in[8];
    const float* b2    = (const float*)d_in[9];
    float* out = (float*)d_out;
    float* ws  = (float*)d_ws;

    prep_kernel<<<1, 64, 0, stream>>>(ln_w, ln_b, W1, b1, W2, ws);

    int grid = NE / 128;  // 6250, exact
    edge_kernel<<<grid, 512, 0, stream>>>(x, ei, etype, ntype, ws, b2, out);
}

// Round 3
// 115.887 us; speedup vs baseline: 4.9933x; 1.3442x over previous
//
#include <hip/hip_runtime.h>
#include <hip/hip_bf16.h>

#define NN 50000
#define NE 800000
#define C 128
#define HH 64
#define TIN 288
#define LN_EPS 1e-5f

typedef __attribute__((ext_vector_type(8))) short bf16x8;
typedef __attribute__((ext_vector_type(4))) float f32x4;

// ws layout (bytes):
//   [0,256)           sj[64] f32
//   [256,512)         cj[64] f32
//   [512,37376)       B1frag: [kt=9][nt=4][lane=64][j=8] bf16 (36864 B)
//   [37376,39424)     B2frag: [kt=2][lane=64][j=8] bf16       (2048 B)
//   [39424,239424)    S[50000] f32  (per-node sum)
//   [239424,439424)   Q[50000] f32  (per-node sumsq)
//   [439424,13239424) x_bf[50000][128] bf16   (optional, if ws fits)
#define S_OFF 39424
#define Q_OFF 239424
#define XBF_OFF 439424
#define WS_NEED (XBF_OFF + (size_t)NN * C * 2)

__device__ __forceinline__ short f2bf(float f) {
    __hip_bfloat16 h = __float2bfloat16(f);
    return __builtin_bit_cast(short, h);
}

__global__ void prep_weights(const float* __restrict__ ln_w,
                             const float* __restrict__ ln_b,
                             const float* __restrict__ W1,
                             const float* __restrict__ b1,
                             const float* __restrict__ W2,
                             float* __restrict__ ws) {
    int l = threadIdx.x;        // 64 lanes
    int m = l & 15, g = l >> 4;
    float s = 0.f, c = 0.f;
    for (int k = 0; k < TIN; ++k) {
        float w = W1[k * HH + l];
        s += ln_w[k] * w;
        c += ln_b[k] * w;
    }
    ws[l] = s;
    ws[64 + l] = c + b1[l];

    short* B1 = (short*)((char*)ws + 512);
    for (int kt = 0; kt < 9; ++kt)
        for (int nt = 0; nt < 4; ++nt)
            for (int j = 0; j < 8; ++j) {
                int k = 32 * kt + 8 * g + j;
                int n = 16 * nt + m;
                B1[((kt * 4 + nt) * 64 + l) * 8 + j] = f2bf(ln_w[k] * W1[k * HH + n]);
            }
    short* B2 = B1 + 18432;
    for (int kt = 0; kt < 2; ++kt)
        for (int j = 0; j < 8; ++j) {
            int k = 32 * kt + 8 * g + j;
            B2[(kt * 64 + l) * 8 + j] = f2bf(W2[k * 16 + m]);
        }
}

// one wave per node: S/Q reduction + optional bf16 conversion
__global__ void prep_nodes(const float* __restrict__ x,
                           float* __restrict__ S,
                           float* __restrict__ Q,
                           unsigned short* __restrict__ x_bf) {
    int n = blockIdx.x * 4 + (threadIdx.x >> 6);
    if (n >= NN) return;
    int l = threadIdx.x & 63;
    float2 v = *(const float2*)(x + (size_t)n * C + 2 * l);
    if (x_bf) {
        ushort2 o;
        o.x = (unsigned short)f2bf(v.x);
        o.y = (unsigned short)f2bf(v.y);
        *(ushort2*)(x_bf + (size_t)n * C + 2 * l) = o;
    }
    float s = v.x + v.y;
    float q = v.x * v.x + v.y * v.y;
#pragma unroll
    for (int d = 1; d < 64; d <<= 1) {
        s += __shfl_xor(s, d);
        q += __shfl_xor(q, d);
    }
    if (l == 0) { S[n] = s; Q[n] = q; }
}

template <bool XBF>
__global__ __launch_bounds__(512, 8) void edge_kernel(
    const void* __restrict__ xv,      // f32 x or bf16 x_bf
    const int* __restrict__ ei,       // [2][E]
    const int* __restrict__ etype,    // [E]
    const int* __restrict__ ntype,    // [N]
    const float* __restrict__ ws,     // sj/cj (+B src staged separately)
    const float* __restrict__ S,
    const float* __restrict__ Q,
    const float* __restrict__ b2,     // [16]
    float* __restrict__ out) {        // [E][16]
    // LDS: B1 [0,18432) shorts | B2 [18432,19456).
    // hT (8 waves * 1024 shorts) ALIASES B1[0,8192) after GEMM1's barrier.
    __shared__ __align__(16) short lds_s[19456];

    int tid = threadIdx.x;
    {   // stage B1+B2 fragments (38912 B) into LDS
        const float4* src = (const float4*)((const char*)ws + 512);
        float4* dst = (float4*)lds_s;
        for (int i = tid; i < 2432; i += 512) dst[i] = src[i];
    }
    __syncthreads();

    int wave = tid >> 6, lane = tid & 63;
    int m = lane & 15, g = lane >> 4;
    int tile = blockIdx.x * 128 + wave * 16;
    int e = tile + m;

    int row = ei[e];
    int col = ei[NE + e];
    int ntr = ntype[row], ntc = ntype[col], et = etype[e];

    // LN stats from per-node tables (+3 for the three one-hot 1.0 entries)
    float sum = S[row] + S[col] + 3.0f;
    float sumsq = Q[row] + Q[col] + 3.0f;
    float mu = sum * (1.0f / TIN);
    float var = sumsq * (1.0f / TIN) - mu * mu;
    float rstd = rsqrtf(var + LN_EPS);

    f32x4 acc0 = {0.f, 0.f, 0.f, 0.f};
    f32x4 acc1 = {0.f, 0.f, 0.f, 0.f};
    f32x4 acc2t = {0.f, 0.f, 0.f, 0.f};
    f32x4 acc3 = {0.f, 0.f, 0.f, 0.f};

#pragma unroll
    for (int kt = 0; kt < 9; ++kt) {
        bf16x8 af;
        if (kt < 8) {
            if (XBF) {
                const unsigned short* xb = (const unsigned short*)xv;
                af = *(const bf16x8*)(xb + (size_t)(kt < 4 ? row : col) * C +
                                      (kt & 3) * 32 + g * 8);
            } else {
                const float* xf = (const float*)xv;
                const float* base = xf + (size_t)(kt < 4 ? row : col) * C +
                                    (kt & 3) * 32 + g * 8;
                float4 p0 = *(const float4*)base;
                float4 p1 = *(const float4*)(base + 4);
                float v[8] = {p0.x, p0.y, p0.z, p0.w, p1.x, p1.y, p1.z, p1.w};
#pragma unroll
                for (int j = 0; j < 8; ++j) af[j] = f2bf(v[j]);
            }
        } else {
            int sel = (g == 0) ? ntr : (g == 1) ? ntc : (g == 2) ? et : (et - 8);
#pragma unroll
            for (int j = 0; j < 8; ++j) af[j] = (j == sel) ? (short)0x3F80 : (short)0;
        }
        const bf16x8* Bk = (const bf16x8*)(lds_s + kt * 2048);
        acc0 = __builtin_amdgcn_mfma_f32_16x16x32_bf16(af, Bk[0 * 64 + lane], acc0, 0, 0, 0);
        acc1 = __builtin_amdgcn_mfma_f32_16x16x32_bf16(af, Bk[1 * 64 + lane], acc1, 0, 0, 0);
        acc2t = __builtin_amdgcn_mfma_f32_16x16x32_bf16(af, Bk[2 * 64 + lane], acc2t, 0, 0, 0);
        acc3 = __builtin_amdgcn_mfma_f32_16x16x32_bf16(af, Bk[3 * 64 + lane], acc3, 0, 0, 0);
    }

    // C rows of this lane are edges 4g+i; pull their stats
    float muv[4], rsv[4];
#pragma unroll
    for (int i = 0; i < 4; ++i) {
        muv[i] = __shfl(mu, 4 * g + i);
        rsv[i] = __shfl(rstd, 4 * g + i);
    }
    float sjv[4], cjv[4];
#pragma unroll
    for (int nt = 0; nt < 4; ++nt) {
        sjv[nt] = ws[16 * nt + m];
        cjv[nt] = ws[64 + 16 * nt + m];
    }

    __syncthreads();  // all waves done reading B1 -> hT may overlay it

    // hid = relu(rstd*(G - mu*s) + c) -> bf16 -> swizzled LDS transpose
    short* hTw = lds_s + wave * 1024;
    f32x4 accs[4] = {acc0, acc1, acc2t, acc3};
#pragma unroll
    for (int nt = 0; nt < 4; ++nt) {
#pragma unroll
        for (int i = 0; i < 4; ++i) {
            float hv = rsv[i] * (accs[nt][i] - muv[i] * sjv[nt]) + cjv[nt];
            hv = fmaxf(hv, 0.0f);
            int erow = 4 * g + i;
            int sidx = (erow * 64 + 16 * nt + m) ^ ((erow & 7) << 3);
            hTw[sidx] = f2bf(hv);
        }
    }
    // wave reads only its own hT slice -> no barrier needed (lgkmcnt orders RAW)

    // GEMM2: [16 edges x 64] @ W2[64][16]
    f32x4 o = {0.f, 0.f, 0.f, 0.f};
    const bf16x8* B2f = (const bf16x8*)(lds_s + 18432);
#pragma unroll
    for (int kt2 = 0; kt2 < 2; ++kt2) {
        int sbase = (m * 64 + kt2 * 32 + 8 * g) ^ ((m & 7) << 3);
        bf16x8 a2 = *(const bf16x8*)(hTw + sbase);
        o = __builtin_amdgcn_mfma_f32_16x16x32_bf16(a2, B2f[kt2 * 64 + lane], o, 0, 0, 0);
    }

    // epilogue: +b2, per-4 softmax across lanes, out = I - softmax
    float b2v = b2[m];
    int r = m >> 2, cc = m & 3;
    float diag = (cc == r) ? 1.0f : 0.0f;
#pragma unroll
    for (int i = 0; i < 4; ++i) {
        float v = o[i] + b2v;
        float mx = fmaxf(v, __shfl_xor(v, 1));
        mx = fmaxf(mx, __shfl_xor(mx, 2));
        float ev = __expf(v - mx);
        float s = ev + __shfl_xor(ev, 1);
        s += __shfl_xor(s, 2);
        out[(size_t)(tile + 4 * g + i) * 16 + m] = diag - ev / s;
    }
}

extern "C" void kernel_launch(void* const* d_in, const int* in_sizes, int n_in,
                              void* d_out, int out_size, void* d_ws, size_t ws_size,
                              hipStream_t stream) {
    const float* x     = (const float*)d_in[0];
    const int*   ei    = (const int*)d_in[1];
    const int*   etype = (const int*)d_in[2];
    const int*   ntype = (const int*)d_in[3];
    const float* ln_w  = (const float*)d_in[4];
    const float* ln_b  = (const float*)d_in[5];
    const float* W1    = (const float*)d_in[6];
    const float* b1    = (const float*)d_in[7];
    const float* W2    = (const float*)d_in[8];
    const float* b2    = (const float*)d_in[9];
    float* out = (float*)d_out;
    float* ws  = (float*)d_ws;

    float* S = (float*)((char*)d_ws + S_OFF);
    float* Q = (float*)((char*)d_ws + Q_OFF);
    unsigned short* x_bf = (unsigned short*)((char*)d_ws + XBF_OFF);
    bool use_xbf = ws_size >= WS_NEED;

    prep_weights<<<1, 64, 0, stream>>>(ln_w, ln_b, W1, b1, W2, ws);
    prep_nodes<<<(NN + 3) / 4, 256, 0, stream>>>(x, S, Q, use_xbf ? x_bf : nullptr);

    int grid = NE / 128;  // 6250, exact
    if (use_xbf)
        edge_kernel<true><<<grid, 512, 0, stream>>>(x_bf, ei, etype, ntype, ws,
                                                    S, Q, b2, out);
    else
        edge_kernel<false><<<grid, 512, 0, stream>>>(x, ei, etype, ntype, ws,
                                                     S, Q, b2, out);
}